// Round 4
// baseline (1915.731 us; speedup 1.0000x reference)
//
#include <hip/hip_runtime.h>
#include <hip/hip_bf16.h>

#define N_NODES      150000
#define N_FRAG_NODES 300000
#define N_FRAGS      30000
#define NEDGE        1200000
#define D            128

// ---------------- segment starts of sorted batch ----------------
__global__ void k_starts(const int* __restrict__ batch, int* __restrict__ startb) {
    int b = blockIdx.x * blockDim.x + threadIdx.x;
    if (b > N_FRAGS) return;
    int lo = 0, hi = N_FRAG_NODES;
    while (lo < hi) { int mid = (lo + hi) >> 1; if (batch[mid] < b) lo = mid + 1; else hi = mid; }
    startb[b] = lo;
}

// ---------------- frag[b] = mean_{j in seg(b)} x[mapper[j]] ----------------
__global__ void k_frag_mean(const float* __restrict__ x, const int* __restrict__ mapper,
                            const int* __restrict__ startb, float* __restrict__ frag) {
    int b = blockIdx.x; int d = threadIdx.x;
    int s = startb[b], e = startb[b + 1];
    float sum = 0.f;
    for (int j = s; j < e; ++j) sum += x[(size_t)mapper[j] * D + d];
    float c = (float)(e - s); if (c < 1.f) c = 1.f;
    frag[(size_t)b * D + d] = sum / c;
}

// ---------------- dst[r] = act(src[r] @ W + b); in-place safe ----------------
template <bool RELU, bool BIAS>
__global__ void k_rowmat(const float* __restrict__ src, const float* __restrict__ W,
                         const float* __restrict__ bias, float* __restrict__ dst, int rows) {
    const int R = 8;
    __shared__ float Wl[D * D];     // 64 KB
    __shared__ float rowl[R][D];    // 4 KB
    int d = threadIdx.x;            // 128 threads
    for (int k = d; k < D * D; k += 128) Wl[k] = W[k];
    float bv = BIAS ? bias[d] : 0.f;
    __syncthreads();
    for (int r0 = blockIdx.x * R; r0 < rows; r0 += gridDim.x * R) {
        int rmax = min(R, rows - r0);
        for (int rr = 0; rr < rmax; ++rr) rowl[rr][d] = src[(size_t)(r0 + rr) * D + d];
        __syncthreads();
        float acc[R];
        #pragma unroll
        for (int rr = 0; rr < R; ++rr) acc[rr] = 0.f;
        #pragma unroll 4
        for (int k = 0; k < D; ++k) {
            float w = Wl[k * D + d];
            #pragma unroll
            for (int rr = 0; rr < R; ++rr) acc[rr] = fmaf(rowl[rr][k], w, acc[rr]);
        }
        __syncthreads();
        for (int rr = 0; rr < rmax; ++rr) {
            float v = acc[rr] + bv;
            if (RELU) v = fmaxf(v, 0.f);
            dst[(size_t)(r0 + rr) * D + d] = v;
        }
    }
}

// ---------------- histogram ----------------
__global__ void k_hist(const int* __restrict__ idx, int n, int* __restrict__ cnt) {
    int i = blockIdx.x * blockDim.x + threadIdx.x;
    if (i < n) atomicAdd(&cnt[idx[i]], 1);
}

// ---------------- single-block exclusive scan: starts[0..n], starts[n]=total ----------------
__global__ void k_scan(const int* __restrict__ cnt, int n, int* __restrict__ starts) {
    __shared__ int buf[1024];
    __shared__ int carry;
    int tid = threadIdx.x;
    if (tid == 0) carry = 0;
    __syncthreads();
    for (int base = 0; base < n; base += 1024) {
        int v = (base + tid < n) ? cnt[base + tid] : 0;
        buf[tid] = v;
        __syncthreads();
        for (int off = 1; off < 1024; off <<= 1) {
            int t = (tid >= off) ? buf[tid - off] : 0;
            __syncthreads();
            buf[tid] += t;
            __syncthreads();
        }
        if (base + tid < n) starts[base + tid] = carry + buf[tid] - v;  // exclusive
        __syncthreads();
        if (tid == 0) carry += buf[1023];
        __syncthreads();
    }
    if (tid == 0) starts[n] = carry;
}

// ---------------- CSR fill ----------------
__global__ void k_fill(const int* __restrict__ idx, int n, const int* __restrict__ starts,
                       int* __restrict__ cnt, int* __restrict__ perm) {
    int i = blockIdx.x * blockDim.x + threadIdx.x;
    if (i >= n) return;
    int k = idx[i];
    int pos = atomicSub(&cnt[k], 1) - 1;
    perm[starts[k] + pos] = i;
}

// ---------------- pooled[n] = x[n] + mean_{j in mapper-seg(n)} fragu[batch[j]] ----------------
__global__ void k_pool_csr(const float* __restrict__ x, const int* __restrict__ batch,
                           const float* __restrict__ fragu, const int* __restrict__ mstart,
                           const int* __restrict__ mperm, float* __restrict__ pooled) {
    int n = blockIdx.x; int d = threadIdx.x;
    int s = mstart[n], e = mstart[n + 1];
    if (e <= s) { pooled[(size_t)n * D + d] = 0.f; return; }
    float sum = 0.f;
    for (int t = s; t < e; ++t) {
        int b = batch[mperm[t]];
        sum += fragu[(size_t)b * D + d];
    }
    pooled[(size_t)n * D + d] = x[(size_t)n * D + d] + sum / (float)(e - s);
}

// ---------------- dinv[c] = rsqrt(indeg + 1) ----------------
__global__ void k_dinv(const int* __restrict__ cstart, float* __restrict__ dinv) {
    int c = blockIdx.x * blockDim.x + threadIdx.x;
    if (c >= N_FRAG_NODES) return;
    float deg = (float)(cstart[c + 1] - cstart[c] + 1);
    dinv[c] = rsqrtf(deg);
}

// ---------------- GCN gather -> f32 x_out ----------------
__global__ void k_gcn_gather(const int* __restrict__ erow, const int* __restrict__ mapper,
                             const int* __restrict__ cstart, const int* __restrict__ cperm,
                             const float* __restrict__ pw, const float* __restrict__ dinv,
                             const float* __restrict__ bgcn, float* __restrict__ xout) {
    int c = blockIdx.x; int d = threadIdx.x;
    int s = cstart[c], e = cstart[c + 1];
    float dc = dinv[c];
    float acc = 0.f;
    for (int t = s; t < e; ++t) {
        int r = erow[cperm[t]];
        acc += pw[(size_t)mapper[r] * D + d] * dinv[r];
    }
    xout[(size_t)c * D + d] = acc * dc + pw[(size_t)mapper[c] * D + d] * (dc * dc) + bgcn[d];
}

// ---------------- fragment_x[b] = mean_{j in seg(b)} xout[j] ----------------
__global__ void k_frag_x(const float* __restrict__ xout, const int* __restrict__ startb,
                         float* __restrict__ fout) {
    int b = blockIdx.x; int d = threadIdx.x;
    int s = startb[b], e = startb[b + 1];
    float sum = 0.f;
    for (int j = s; j < e; ++j) sum += xout[(size_t)j * D + d];
    fout[(size_t)b * D + d] = (e > s) ? sum / (float)(e - s) : 0.f;
}

extern "C" void kernel_launch(void* const* d_in, const int* in_sizes, int n_in,
                              void* d_out, int out_size, void* d_ws, size_t ws_size,
                              hipStream_t stream) {
    const float* x      = (const float*)d_in[0];         // f32 [N_NODES, D]
    const int*   mapper = (const int*)d_in[1];
    const int*   batch  = (const int*)d_in[2];
    const int*   erow   = (const int*)d_in[3];           // edge_index[0] (source)
    const int*   ecol   = erow + NEDGE;                  // edge_index[1] (target)
    const float* W_u    = (const float*)d_in[4];
    const float* b_u    = (const float*)d_in[5];
    const float* W_gcn  = (const float*)d_in[6];
    const float* b_gcn  = (const float*)d_in[7];
    // d_in[8] = i (always 0 here)

    float* fout = (float*)d_out;                         // f32 [N_FRAGS, D]
    float* xout = fout + (size_t)N_FRAGS * D;            // f32 [N_FRAG_NODES, D]

    // ---- workspace layout (~103 MB; ws proven >= 248 MB by round-1/2 behavior) ----
    float* frag   = (float*)d_ws;                        // 3,840,000 f32  (frag -> fragu in place)
    float* pooled = frag + (size_t)N_FRAGS * D;          // 19,200,000 f32 (pooled -> pw in place)
    float* dinv   = pooled + (size_t)N_NODES * D;        // 300,000 f32
    int*   startb = (int*)(dinv + N_FRAG_NODES);         // 30,001
    int*   mstart = startb + (N_FRAGS + 1);              // 150,001
    int*   cstart = mstart + (N_NODES + 1);              // 300,001
    int*   mcnt   = cstart + (N_FRAG_NODES + 1);         // 150,000  (memset 0)
    int*   ccnt   = mcnt + N_NODES;                      // 300,000  (memset 0)
    int*   mperm  = ccnt + N_FRAG_NODES;                 // 300,000
    int*   cperm  = mperm + N_FRAG_NODES;                // 1,200,000

    hipMemsetAsync(mcnt, 0, (size_t)(N_NODES + N_FRAG_NODES) * sizeof(int), stream);

    // fragment means + MLP
    k_starts<<<(N_FRAGS + 256) / 256, 256, 0, stream>>>(batch, startb);
    k_frag_mean<<<N_FRAGS, D, 0, stream>>>(x, mapper, startb, frag);
    k_rowmat<true, true><<<1024, D, 0, stream>>>(frag, W_u, b_u, frag, N_FRAGS);      // fragu

    // mapper CSR
    k_hist<<<(N_FRAG_NODES + 255) / 256, 256, 0, stream>>>(mapper, N_FRAG_NODES, mcnt);
    k_scan<<<1, 1024, 0, stream>>>(mcnt, N_NODES, mstart);
    k_fill<<<(N_FRAG_NODES + 255) / 256, 256, 0, stream>>>(mapper, N_FRAG_NODES, mstart, mcnt, mperm);

    // node pooling + W_gcn
    k_pool_csr<<<N_NODES, D, 0, stream>>>(x, batch, frag, mstart, mperm, pooled);
    k_rowmat<false, false><<<1024, D, 0, stream>>>(pooled, W_gcn, nullptr, pooled, N_NODES);  // pw

    // edge CSR (by target col)
    k_hist<<<(NEDGE + 255) / 256, 256, 0, stream>>>(ecol, NEDGE, ccnt);
    k_scan<<<1, 1024, 0, stream>>>(ccnt, N_FRAG_NODES, cstart);
    k_fill<<<(NEDGE + 255) / 256, 256, 0, stream>>>(ecol, NEDGE, cstart, ccnt, cperm);
    k_dinv<<<(N_FRAG_NODES + 255) / 256, 256, 0, stream>>>(cstart, dinv);

    // GCN aggregation (gather) -> f32 x_out
    k_gcn_gather<<<N_FRAG_NODES, D, 0, stream>>>(erow, mapper, cstart, cperm,
                                                 pooled, dinv, b_gcn, xout);
    // fragment mean of x_out
    k_frag_x<<<N_FRAGS, D, 0, stream>>>(xout, startb, fout);
}

// Round 5
// 1167.000 us; speedup vs baseline: 1.6416x; 1.6416x over previous
//
#include <hip/hip_runtime.h>
#include <hip/hip_bf16.h>

#define N_NODES      150000
#define N_FRAG_NODES 300000
#define N_FRAGS      30000
#define NEDGE        1200000
#define D            128
#define SCAN_TILE    1024

// ---------------- segment starts of sorted batch ----------------
__global__ void k_starts(const int* __restrict__ batch, int* __restrict__ startb) {
    int b = blockIdx.x * blockDim.x + threadIdx.x;
    if (b > N_FRAGS) return;
    int lo = 0, hi = N_FRAG_NODES;
    while (lo < hi) { int mid = (lo + hi) >> 1; if (batch[mid] < b) lo = mid + 1; else hi = mid; }
    startb[b] = lo;
}

// ---------------- frag[b] = mean_{j in seg(b)} x[mapper[j]] ----------------
__global__ void k_frag_mean(const float* __restrict__ x, const int* __restrict__ mapper,
                            const int* __restrict__ startb, float* __restrict__ frag) {
    int b = blockIdx.x; int d = threadIdx.x;
    int s = startb[b], e = startb[b + 1];
    float sum = 0.f;
    for (int j = s; j < e; ++j) sum += x[(size_t)mapper[j] * D + d];
    float c = (float)(e - s); if (c < 1.f) c = 1.f;
    frag[(size_t)b * D + d] = sum / c;
}

// ---------------- dst[r] = act(src[r] @ W + b); in-place safe ----------------
template <bool RELU, bool BIAS>
__global__ void k_rowmat(const float* __restrict__ src, const float* __restrict__ W,
                         const float* __restrict__ bias, float* __restrict__ dst, int rows) {
    const int R = 8;
    __shared__ float Wl[D * D];     // 64 KB
    __shared__ float rowl[R][D];    // 4 KB
    int d = threadIdx.x;            // 128 threads
    for (int k = d; k < D * D; k += 128) Wl[k] = W[k];
    float bv = BIAS ? bias[d] : 0.f;
    __syncthreads();
    for (int r0 = blockIdx.x * R; r0 < rows; r0 += gridDim.x * R) {
        int rmax = min(R, rows - r0);
        for (int rr = 0; rr < rmax; ++rr) rowl[rr][d] = src[(size_t)(r0 + rr) * D + d];
        __syncthreads();
        float acc[R];
        #pragma unroll
        for (int rr = 0; rr < R; ++rr) acc[rr] = 0.f;
        #pragma unroll 4
        for (int k = 0; k < D; ++k) {
            float w = Wl[k * D + d];
            #pragma unroll
            for (int rr = 0; rr < R; ++rr) acc[rr] = fmaf(rowl[rr][k], w, acc[rr]);
        }
        __syncthreads();
        for (int rr = 0; rr < rmax; ++rr) {
            float v = acc[rr] + bv;
            if (RELU) v = fmaxf(v, 0.f);
            dst[(size_t)(r0 + rr) * D + d] = v;
        }
    }
}

// ---------------- histogram ----------------
__global__ void k_hist(const int* __restrict__ idx, int n, int* __restrict__ cnt) {
    int i = blockIdx.x * blockDim.x + threadIdx.x;
    if (i < n) atomicAdd(&cnt[idx[i]], 1);
}

// ---------------- hierarchical exclusive scan, phase A: per-tile scan ----------------
__global__ void k_scan_tile(const int* __restrict__ cnt, int n, int* __restrict__ starts,
                            int* __restrict__ tsum) {
    __shared__ int buf[SCAN_TILE];
    int tid = threadIdx.x;                       // 1024 threads
    int i = blockIdx.x * SCAN_TILE + tid;
    int v = (i < n) ? cnt[i] : 0;
    buf[tid] = v;
    __syncthreads();
    for (int off = 1; off < SCAN_TILE; off <<= 1) {
        int t = (tid >= off) ? buf[tid - off] : 0;
        __syncthreads();
        buf[tid] += t;
        __syncthreads();
    }
    if (i < n) starts[i] = buf[tid] - v;         // exclusive within tile
    if (tid == SCAN_TILE - 1) tsum[blockIdx.x] = buf[tid];
}

// ---------------- phase B: one-block exclusive scan of tile sums (ntiles <= 1024) ----------------
__global__ void k_scan_tsum(int* __restrict__ tsum, int ntiles, int* __restrict__ starts, int n) {
    __shared__ int buf[SCAN_TILE];
    int tid = threadIdx.x;
    int v = (tid < ntiles) ? tsum[tid] : 0;
    buf[tid] = v;
    __syncthreads();
    for (int off = 1; off < SCAN_TILE; off <<= 1) {
        int t = (tid >= off) ? buf[tid - off] : 0;
        __syncthreads();
        buf[tid] += t;
        __syncthreads();
    }
    if (tid < ntiles) tsum[tid] = buf[tid] - v;  // exclusive tile offsets
    if (tid == SCAN_TILE - 1) starts[n] = buf[tid];  // grand total
}

// ---------------- phase C: add tile offsets ----------------
__global__ void k_scan_add(int* __restrict__ starts, int n, const int* __restrict__ tsum) {
    int i = blockIdx.x * blockDim.x + threadIdx.x;
    if (i < n) starts[i] += tsum[i >> 10];
}

// ---------------- CSR fill ----------------
__global__ void k_fill(const int* __restrict__ idx, int n, const int* __restrict__ starts,
                       int* __restrict__ cnt, int* __restrict__ perm) {
    int i = blockIdx.x * blockDim.x + threadIdx.x;
    if (i >= n) return;
    int k = idx[i];
    int pos = atomicSub(&cnt[k], 1) - 1;
    perm[starts[k] + pos] = i;
}

// ---------------- pooled[n] = x[n] + mean_{j in mapper-seg(n)} fragu[batch[j]] ----------------
__global__ void k_pool_csr(const float* __restrict__ x, const int* __restrict__ batch,
                           const float* __restrict__ fragu, const int* __restrict__ mstart,
                           const int* __restrict__ mperm, float* __restrict__ pooled) {
    int n = blockIdx.x; int d = threadIdx.x;
    int s = mstart[n], e = mstart[n + 1];
    if (e <= s) { pooled[(size_t)n * D + d] = 0.f; return; }
    float sum = 0.f;
    for (int t = s; t < e; ++t) {
        int b = batch[mperm[t]];
        sum += fragu[(size_t)b * D + d];
    }
    pooled[(size_t)n * D + d] = x[(size_t)n * D + d] + sum / (float)(e - s);
}

// ---------------- dinv[c] = rsqrt(indeg + 1) ----------------
__global__ void k_dinv(const int* __restrict__ cstart, float* __restrict__ dinv) {
    int c = blockIdx.x * blockDim.x + threadIdx.x;
    if (c >= N_FRAG_NODES) return;
    float deg = (float)(cstart[c + 1] - cstart[c] + 1);
    dinv[c] = rsqrtf(deg);
}

// ---------------- GCN gather -> f32 x_out ----------------
__global__ void k_gcn_gather(const int* __restrict__ erow, const int* __restrict__ mapper,
                             const int* __restrict__ cstart, const int* __restrict__ cperm,
                             const float* __restrict__ pw, const float* __restrict__ dinv,
                             const float* __restrict__ bgcn, float* __restrict__ xout) {
    int c = blockIdx.x; int d = threadIdx.x;
    int s = cstart[c], e = cstart[c + 1];
    float dc = dinv[c];
    float acc = 0.f;
    for (int t = s; t < e; ++t) {
        int r = erow[cperm[t]];
        acc += pw[(size_t)mapper[r] * D + d] * dinv[r];
    }
    xout[(size_t)c * D + d] = acc * dc + pw[(size_t)mapper[c] * D + d] * (dc * dc) + bgcn[d];
}

// ---------------- fragment_x[b] = mean_{j in seg(b)} xout[j] ----------------
__global__ void k_frag_x(const float* __restrict__ xout, const int* __restrict__ startb,
                         float* __restrict__ fout) {
    int b = blockIdx.x; int d = threadIdx.x;
    int s = startb[b], e = startb[b + 1];
    float sum = 0.f;
    for (int j = s; j < e; ++j) sum += xout[(size_t)j * D + d];
    fout[(size_t)b * D + d] = (e > s) ? sum / (float)(e - s) : 0.f;
}

static inline void run_scan(const int* cnt, int n, int* starts, int* tsum, hipStream_t stream) {
    int ntiles = (n + SCAN_TILE - 1) / SCAN_TILE;      // <= 1024
    k_scan_tile<<<ntiles, SCAN_TILE, 0, stream>>>(cnt, n, starts, tsum);
    k_scan_tsum<<<1, SCAN_TILE, 0, stream>>>(tsum, ntiles, starts, n);
    k_scan_add<<<(n + 255) / 256, 256, 0, stream>>>(starts, n, tsum);
}

extern "C" void kernel_launch(void* const* d_in, const int* in_sizes, int n_in,
                              void* d_out, int out_size, void* d_ws, size_t ws_size,
                              hipStream_t stream) {
    const float* x      = (const float*)d_in[0];         // f32 [N_NODES, D]
    const int*   mapper = (const int*)d_in[1];
    const int*   batch  = (const int*)d_in[2];
    const int*   erow   = (const int*)d_in[3];           // edge_index[0] (source)
    const int*   ecol   = erow + NEDGE;                  // edge_index[1] (target)
    const float* W_u    = (const float*)d_in[4];
    const float* b_u    = (const float*)d_in[5];
    const float* W_gcn  = (const float*)d_in[6];
    const float* b_gcn  = (const float*)d_in[7];
    // d_in[8] = i (always 0 here)

    float* fout = (float*)d_out;                         // f32 [N_FRAGS, D]
    float* xout = fout + (size_t)N_FRAGS * D;            // f32 [N_FRAG_NODES, D]

    // ---- workspace layout (~102 MB; ws proven >= 248 MB by round-1/2 behavior) ----
    float* frag   = (float*)d_ws;                        // 3,840,000 f32  (frag -> fragu in place)
    float* pooled = frag + (size_t)N_FRAGS * D;          // 19,200,000 f32 (pooled -> pw in place)
    float* dinv   = pooled + (size_t)N_NODES * D;        // 300,000 f32
    int*   startb = (int*)(dinv + N_FRAG_NODES);         // 30,001
    int*   mstart = startb + (N_FRAGS + 1);              // 150,001
    int*   cstart = mstart + (N_NODES + 1);              // 300,001
    int*   mcnt   = cstart + (N_FRAG_NODES + 1);         // 150,000  (memset 0)
    int*   ccnt   = mcnt + N_NODES;                      // 300,000  (memset 0)
    int*   mperm  = ccnt + N_FRAG_NODES;                 // 300,000
    int*   cperm  = mperm + N_FRAG_NODES;                // 1,200,000
    int*   tsum   = cperm + NEDGE;                       // 1,024

    hipMemsetAsync(mcnt, 0, (size_t)(N_NODES + N_FRAG_NODES) * sizeof(int), stream);

    // fragment means + MLP
    k_starts<<<(N_FRAGS + 256) / 256, 256, 0, stream>>>(batch, startb);
    k_frag_mean<<<N_FRAGS, D, 0, stream>>>(x, mapper, startb, frag);
    k_rowmat<true, true><<<1024, D, 0, stream>>>(frag, W_u, b_u, frag, N_FRAGS);      // fragu

    // mapper CSR
    k_hist<<<(N_FRAG_NODES + 255) / 256, 256, 0, stream>>>(mapper, N_FRAG_NODES, mcnt);
    run_scan(mcnt, N_NODES, mstart, tsum, stream);
    k_fill<<<(N_FRAG_NODES + 255) / 256, 256, 0, stream>>>(mapper, N_FRAG_NODES, mstart, mcnt, mperm);

    // node pooling + W_gcn
    k_pool_csr<<<N_NODES, D, 0, stream>>>(x, batch, frag, mstart, mperm, pooled);
    k_rowmat<false, false><<<1024, D, 0, stream>>>(pooled, W_gcn, nullptr, pooled, N_NODES);  // pw

    // edge CSR (by target col)
    k_hist<<<(NEDGE + 255) / 256, 256, 0, stream>>>(ecol, NEDGE, ccnt);
    run_scan(ccnt, N_FRAG_NODES, cstart, tsum, stream);
    k_fill<<<(NEDGE + 255) / 256, 256, 0, stream>>>(ecol, NEDGE, cstart, ccnt, cperm);
    k_dinv<<<(N_FRAG_NODES + 255) / 256, 256, 0, stream>>>(cstart, dinv);

    // GCN aggregation (gather) -> f32 x_out
    k_gcn_gather<<<N_FRAG_NODES, D, 0, stream>>>(erow, mapper, cstart, cperm,
                                                 pooled, dinv, b_gcn, xout);
    // fragment mean of x_out
    k_frag_x<<<N_FRAGS, D, 0, stream>>>(xout, startb, fout);
}

// Round 6
// 843.864 us; speedup vs baseline: 2.2702x; 1.3829x over previous
//
#include <hip/hip_runtime.h>
#include <hip/hip_bf16.h>

#define N_NODES      150000
#define N_FRAG_NODES 300000
#define N_FRAGS      30000
#define NEDGE        1200000
#define D            128
#define DV           32          // D/4 float4s per row
#define SCAN_TILE    1024

// ---------------- segment starts of sorted batch ----------------
__global__ void k_starts(const int* __restrict__ batch, int* __restrict__ startb) {
    int b = blockIdx.x * blockDim.x + threadIdx.x;
    if (b > N_FRAGS) return;
    int lo = 0, hi = N_FRAG_NODES;
    while (lo < hi) { int mid = (lo + hi) >> 1; if (batch[mid] < b) lo = mid + 1; else hi = mid; }
    startb[b] = lo;
}

// ---------------- frag[b] = mean_{j in seg(b)} x[mapper[j]]  (32-lane group per b, float4) ----------------
__global__ void k_frag_mean(const float* __restrict__ x, const int* __restrict__ mapper,
                            const int* __restrict__ startb, float* __restrict__ frag) {
    int g = threadIdx.x >> 5, lane = threadIdx.x & 31;
    int b = blockIdx.x * 8 + g;
    if (b >= N_FRAGS) return;
    const float4* x4 = (const float4*)x;
    int s = startb[b], e = startb[b + 1];
    float4 sum = {0.f, 0.f, 0.f, 0.f};
    for (int j = s; j < e; ++j) {
        int m = mapper[j];
        float4 v = x4[(size_t)m * DV + lane];
        sum.x += v.x; sum.y += v.y; sum.z += v.z; sum.w += v.w;
    }
    float c = (float)(e - s); if (c < 1.f) c = 1.f;
    float inv = 1.f / c;
    float4 r = {sum.x * inv, sum.y * inv, sum.z * inv, sum.w * inv};
    ((float4*)frag)[(size_t)b * DV + lane] = r;
}

// ---------------- dst[r] = act(src[r] @ W + b); in-place safe ----------------
template <bool RELU, bool BIAS>
__global__ void k_rowmat(const float* __restrict__ src, const float* __restrict__ W,
                         const float* __restrict__ bias, float* __restrict__ dst, int rows) {
    const int R = 8;
    __shared__ float Wl[D * D];     // 64 KB
    __shared__ float rowl[R][D];    // 4 KB
    int d = threadIdx.x;            // 128 threads
    for (int k = d; k < D * D; k += 128) Wl[k] = W[k];
    float bv = BIAS ? bias[d] : 0.f;
    __syncthreads();
    for (int r0 = blockIdx.x * R; r0 < rows; r0 += gridDim.x * R) {
        int rmax = min(R, rows - r0);
        for (int rr = 0; rr < rmax; ++rr) rowl[rr][d] = src[(size_t)(r0 + rr) * D + d];
        __syncthreads();
        float acc[R];
        #pragma unroll
        for (int rr = 0; rr < R; ++rr) acc[rr] = 0.f;
        #pragma unroll 4
        for (int k = 0; k < D; ++k) {
            float w = Wl[k * D + d];
            #pragma unroll
            for (int rr = 0; rr < R; ++rr) acc[rr] = fmaf(rowl[rr][k], w, acc[rr]);
        }
        __syncthreads();
        for (int rr = 0; rr < rmax; ++rr) {
            float v = acc[rr] + bv;
            if (RELU) v = fmaxf(v, 0.f);
            dst[(size_t)(r0 + rr) * D + d] = v;
        }
    }
}

// ---------------- histogram ----------------
__global__ void k_hist(const int* __restrict__ idx, int n, int* __restrict__ cnt) {
    int i = blockIdx.x * blockDim.x + threadIdx.x;
    if (i < n) atomicAdd(&cnt[idx[i]], 1);
}

// ---------------- hierarchical exclusive scan ----------------
__global__ void k_scan_tile(const int* __restrict__ cnt, int n, int* __restrict__ starts,
                            int* __restrict__ tsum) {
    __shared__ int buf[SCAN_TILE];
    int tid = threadIdx.x;
    int i = blockIdx.x * SCAN_TILE + tid;
    int v = (i < n) ? cnt[i] : 0;
    buf[tid] = v;
    __syncthreads();
    for (int off = 1; off < SCAN_TILE; off <<= 1) {
        int t = (tid >= off) ? buf[tid - off] : 0;
        __syncthreads();
        buf[tid] += t;
        __syncthreads();
    }
    if (i < n) starts[i] = buf[tid] - v;
    if (tid == SCAN_TILE - 1) tsum[blockIdx.x] = buf[tid];
}

__global__ void k_scan_tsum(int* __restrict__ tsum, int ntiles, int* __restrict__ starts, int n) {
    __shared__ int buf[SCAN_TILE];
    int tid = threadIdx.x;
    int v = (tid < ntiles) ? tsum[tid] : 0;
    buf[tid] = v;
    __syncthreads();
    for (int off = 1; off < SCAN_TILE; off <<= 1) {
        int t = (tid >= off) ? buf[tid - off] : 0;
        __syncthreads();
        buf[tid] += t;
        __syncthreads();
    }
    if (tid < ntiles) tsum[tid] = buf[tid] - v;
    if (tid == SCAN_TILE - 1) starts[n] = buf[tid];
}

__global__ void k_scan_add(int* __restrict__ starts, int n, const int* __restrict__ tsum) {
    int i = blockIdx.x * blockDim.x + threadIdx.x;
    if (i < n) starts[i] += tsum[i >> 10];
}

// ---------------- mapper CSR fill: store batch[i] directly ----------------
__global__ void k_fill_m(const int* __restrict__ mapper, const int* __restrict__ batch,
                         const int* __restrict__ starts, int* __restrict__ cnt,
                         int* __restrict__ mvals) {
    int i = blockIdx.x * blockDim.x + threadIdx.x;
    if (i >= N_FRAG_NODES) return;
    int k = mapper[i];
    int pos = atomicSub(&cnt[k], 1) - 1;
    mvals[starts[k] + pos] = batch[i];
}

// ---------------- dinv[c] = rsqrt(indeg + 1) ----------------
__global__ void k_dinv(const int* __restrict__ cstart, float* __restrict__ dinv) {
    int c = blockIdx.x * blockDim.x + threadIdx.x;
    if (c >= N_FRAG_NODES) return;
    float deg = (float)(cstart[c + 1] - cstart[c] + 1);
    dinv[c] = rsqrtf(deg);
}

// ---------------- edge CSR fill: store packed (pw row, dinv[src]) ----------------
__global__ void k_fill_e(const int* __restrict__ erow, const int* __restrict__ ecol,
                         const int* __restrict__ mapper, const float* __restrict__ dinv,
                         const int* __restrict__ starts, int* __restrict__ cnt,
                         int2* __restrict__ erecs) {
    int i = blockIdx.x * blockDim.x + threadIdx.x;
    if (i >= NEDGE) return;
    int c = ecol[i], r = erow[i];
    int pos = atomicSub(&cnt[c], 1) - 1;
    int2 rec;
    rec.x = mapper[r];
    rec.y = __float_as_int(dinv[r]);
    erecs[starts[c] + pos] = rec;
}

// ---------------- pooled[n] = x[n] + mean_t fragu[mvals[t]]  (32-lane group per n) ----------------
__global__ void k_pool_csr(const float* __restrict__ x, const float* __restrict__ fragu,
                           const int* __restrict__ mstart, const int* __restrict__ mvals,
                           float* __restrict__ pooled) {
    int g = threadIdx.x >> 5, lane = threadIdx.x & 31;
    int n = blockIdx.x * 8 + g;
    if (n >= N_NODES) return;
    int s = mstart[n], e = mstart[n + 1];
    float4 out = {0.f, 0.f, 0.f, 0.f};
    if (e > s) {
        const float4* f4 = (const float4*)fragu;
        float4 sum = {0.f, 0.f, 0.f, 0.f};
        for (int t = s; t < e; ++t) {
            int b = mvals[t];
            float4 v = f4[(size_t)b * DV + lane];
            sum.x += v.x; sum.y += v.y; sum.z += v.z; sum.w += v.w;
        }
        float inv = 1.f / (float)(e - s);
        float4 xv = ((const float4*)x)[(size_t)n * DV + lane];
        out.x = xv.x + sum.x * inv; out.y = xv.y + sum.y * inv;
        out.z = xv.z + sum.z * inv; out.w = xv.w + sum.w * inv;
    }
    ((float4*)pooled)[(size_t)n * DV + lane] = out;
}

// ---------------- GCN gather (32-lane group per target node, float4, packed recs) ----------------
__global__ void k_gcn_gather(const int* __restrict__ mapper, const int* __restrict__ cstart,
                             const int2* __restrict__ erecs, const float* __restrict__ pw,
                             const float* __restrict__ dinv, const float* __restrict__ bgcn,
                             float* __restrict__ xout) {
    int g = threadIdx.x >> 5, lane = threadIdx.x & 31;
    int c = blockIdx.x * 8 + g;
    if (c >= N_FRAG_NODES) return;
    const float4* pw4 = (const float4*)pw;
    int s = cstart[c], e = cstart[c + 1];
    float4 acc = {0.f, 0.f, 0.f, 0.f};
    for (int t = s; t < e; ++t) {
        int2 rec = erecs[t];
        float w = __int_as_float(rec.y);
        float4 v = pw4[(size_t)rec.x * DV + lane];
        acc.x = fmaf(v.x, w, acc.x); acc.y = fmaf(v.y, w, acc.y);
        acc.z = fmaf(v.z, w, acc.z); acc.w = fmaf(v.w, w, acc.w);
    }
    float dc = dinv[c];
    float dc2 = dc * dc;
    float4 self = pw4[(size_t)mapper[c] * DV + lane];
    float4 bg = ((const float4*)bgcn)[lane];
    float4 o;
    o.x = fmaf(acc.x, dc, fmaf(self.x, dc2, bg.x));
    o.y = fmaf(acc.y, dc, fmaf(self.y, dc2, bg.y));
    o.z = fmaf(acc.z, dc, fmaf(self.z, dc2, bg.z));
    o.w = fmaf(acc.w, dc, fmaf(self.w, dc2, bg.w));
    ((float4*)xout)[(size_t)c * DV + lane] = o;
}

// ---------------- fragment_x[b] = mean_{j in seg(b)} xout[j]  (32-lane group per b) ----------------
__global__ void k_frag_x(const float* __restrict__ xout, const int* __restrict__ startb,
                         float* __restrict__ fout) {
    int g = threadIdx.x >> 5, lane = threadIdx.x & 31;
    int b = blockIdx.x * 8 + g;
    if (b >= N_FRAGS) return;
    const float4* x4 = (const float4*)xout;
    int s = startb[b], e = startb[b + 1];
    float4 sum = {0.f, 0.f, 0.f, 0.f};
    for (int j = s; j < e; ++j) {
        float4 v = x4[(size_t)j * DV + lane];
        sum.x += v.x; sum.y += v.y; sum.z += v.z; sum.w += v.w;
    }
    float4 r = {0.f, 0.f, 0.f, 0.f};
    if (e > s) {
        float inv = 1.f / (float)(e - s);
        r.x = sum.x * inv; r.y = sum.y * inv; r.z = sum.z * inv; r.w = sum.w * inv;
    }
    ((float4*)fout)[(size_t)b * DV + lane] = r;
}

static inline void run_scan(const int* cnt, int n, int* starts, int* tsum, hipStream_t stream) {
    int ntiles = (n + SCAN_TILE - 1) / SCAN_TILE;      // <= 1024
    k_scan_tile<<<ntiles, SCAN_TILE, 0, stream>>>(cnt, n, starts, tsum);
    k_scan_tsum<<<1, SCAN_TILE, 0, stream>>>(tsum, ntiles, starts, n);
    k_scan_add<<<(n + 255) / 256, 256, 0, stream>>>(starts, n, tsum);
}

extern "C" void kernel_launch(void* const* d_in, const int* in_sizes, int n_in,
                              void* d_out, int out_size, void* d_ws, size_t ws_size,
                              hipStream_t stream) {
    const float* x      = (const float*)d_in[0];         // f32 [N_NODES, D]
    const int*   mapper = (const int*)d_in[1];
    const int*   batch  = (const int*)d_in[2];
    const int*   erow   = (const int*)d_in[3];           // edge_index[0] (source)
    const int*   ecol   = erow + NEDGE;                  // edge_index[1] (target)
    const float* W_u    = (const float*)d_in[4];
    const float* b_u    = (const float*)d_in[5];
    const float* W_gcn  = (const float*)d_in[6];
    const float* b_gcn  = (const float*)d_in[7];

    float* fout = (float*)d_out;                         // f32 [N_FRAGS, D]
    float* xout = fout + (size_t)N_FRAGS * D;            // f32 [N_FRAG_NODES, D]

    // ---- workspace layout (~108 MB; 16B alignment for float4/int2 arrays) ----
    int2*  erecs  = (int2*)d_ws;                         // 1,200,000 int2 (9.6 MB)
    float* frag   = (float*)(erecs + NEDGE);             // 3,840,000 f32  (-> fragu in place)
    float* pooled = frag + (size_t)N_FRAGS * D;          // 19,200,000 f32 (-> pw in place)
    float* dinv   = pooled + (size_t)N_NODES * D;        // 300,000 f32
    int*   startb = (int*)(dinv + N_FRAG_NODES);         // 30,001
    int*   mstart = startb + (N_FRAGS + 1);              // 150,001
    int*   cstart = mstart + (N_NODES + 1);              // 300,001
    int*   mcnt   = cstart + (N_FRAG_NODES + 1);         // 150,000  (memset 0)
    int*   ccnt   = mcnt + N_NODES;                      // 300,000  (memset 0)
    int*   mvals  = ccnt + N_FRAG_NODES;                 // 300,000
    int*   tsum   = mvals + N_FRAG_NODES;                // 1,024

    hipMemsetAsync(mcnt, 0, (size_t)(N_NODES + N_FRAG_NODES) * sizeof(int), stream);

    // fragment means + MLP
    k_starts<<<(N_FRAGS + 256) / 256, 256, 0, stream>>>(batch, startb);
    k_frag_mean<<<(N_FRAGS + 7) / 8, 256, 0, stream>>>(x, mapper, startb, frag);
    k_rowmat<true, true><<<1024, D, 0, stream>>>(frag, W_u, b_u, frag, N_FRAGS);      // fragu

    // mapper CSR (values = batch[j])
    k_hist<<<(N_FRAG_NODES + 255) / 256, 256, 0, stream>>>(mapper, N_FRAG_NODES, mcnt);
    run_scan(mcnt, N_NODES, mstart, tsum, stream);
    k_fill_m<<<(N_FRAG_NODES + 255) / 256, 256, 0, stream>>>(mapper, batch, mstart, mcnt, mvals);

    // node pooling + W_gcn
    k_pool_csr<<<(N_NODES + 7) / 8, 256, 0, stream>>>(x, frag, mstart, mvals, pooled);
    k_rowmat<false, false><<<1024, D, 0, stream>>>(pooled, W_gcn, nullptr, pooled, N_NODES);  // pw

    // edge CSR (packed (mapper[src], dinv[src]) records, keyed by target)
    k_hist<<<(NEDGE + 255) / 256, 256, 0, stream>>>(ecol, NEDGE, ccnt);
    run_scan(ccnt, N_FRAG_NODES, cstart, tsum, stream);
    k_dinv<<<(N_FRAG_NODES + 255) / 256, 256, 0, stream>>>(cstart, dinv);
    k_fill_e<<<(NEDGE + 255) / 256, 256, 0, stream>>>(erow, ecol, mapper, dinv, cstart, ccnt, erecs);

    // GCN aggregation (gather) -> f32 x_out
    k_gcn_gather<<<(N_FRAG_NODES + 7) / 8, 256, 0, stream>>>(mapper, cstart, erecs,
                                                             pooled, dinv, b_gcn, xout);
    // fragment mean of x_out
    k_frag_x<<<(N_FRAGS + 7) / 8, 256, 0, stream>>>(xout, startb, fout);
}

// Round 7
// 469.527 us; speedup vs baseline: 4.0801x; 1.7973x over previous
//
#include <hip/hip_runtime.h>
#include <hip/hip_bf16.h>

#define N_NODES      150000
#define N_FRAG_NODES 300000
#define N_FRAGS      30000
#define NEDGE        1200000
#define D            128
#define DV           32          // D/4 float4s per row
#define SCAN_TILE    1024

typedef __attribute__((ext_vector_type(8))) short short8;
typedef __attribute__((ext_vector_type(4))) float f32x4;

__device__ __forceinline__ unsigned short f2bf(float f) {
    unsigned u = __float_as_uint(f);
    u = (u + 0x7FFFu + ((u >> 16) & 1u)) >> 16;   // RNE
    return (unsigned short)u;
}

// ---------------- segment starts of sorted batch ----------------
__global__ void k_starts(const int* __restrict__ batch, int* __restrict__ startb) {
    int b = blockIdx.x * blockDim.x + threadIdx.x;
    if (b > N_FRAGS) return;
    int lo = 0, hi = N_FRAG_NODES;
    while (lo < hi) { int mid = (lo + hi) >> 1; if (batch[mid] < b) lo = mid + 1; else hi = mid; }
    startb[b] = lo;
}

// ---------------- frag[b] = mean_{j in seg(b)} x[mapper[j]]  (32-lane group per b, float4) ----------------
__global__ void k_frag_mean(const float* __restrict__ x, const int* __restrict__ mapper,
                            const int* __restrict__ startb, float* __restrict__ frag) {
    int g = threadIdx.x >> 5, lane = threadIdx.x & 31;
    int b = blockIdx.x * 8 + g;
    if (b >= N_FRAGS) return;
    const float4* x4 = (const float4*)x;
    int s = startb[b], e = startb[b + 1];
    float4 sum = {0.f, 0.f, 0.f, 0.f};
    for (int j = s; j < e; ++j) {
        int m = mapper[j];
        float4 v = x4[(size_t)m * DV + lane];
        sum.x += v.x; sum.y += v.y; sum.z += v.z; sum.w += v.w;
    }
    float c = (float)(e - s); if (c < 1.f) c = 1.f;
    float inv = 1.f / c;
    float4 r = {sum.x * inv, sum.y * inv, sum.z * inv, sum.w * inv};
    ((float4*)frag)[(size_t)b * DV + lane] = r;
}

// ---------------- build MFMA B-fragment table from W[128][128] f32 ----------------
// entry e = (nt*4 + kk)*64 + lane; 8 bf16: W[kk*32 + (lane>>4)*8 + j][nt*16 + (lane&15)]
// (A-frags use the SAME k->(group,slot) convention, so the contraction is
//  correct regardless of the HW's internal k permutation.)
__global__ void k_build_wfrag(const float* __restrict__ W, short* __restrict__ wfrag) {
    int t = threadIdx.x;
    for (int e = t; e < 2048; e += 256) {
        int nt = e >> 8;
        int kk = (e >> 6) & 3;
        int lane = e & 63;
        int col = nt * 16 + (lane & 15);
        int kb = kk * 32 + ((lane >> 4) << 3);
        short8 v;
        #pragma unroll
        for (int j = 0; j < 8; ++j) v[j] = (short)f2bf(W[(kb + j) * D + col]);
        ((short8*)wfrag)[e] = v;
    }
}

// ---------------- dst[r] = act(bf16(src[r]) @ bf16(W) + b) via MFMA; in-place safe ----------------
template <bool RELU, bool BIAS>
__global__ void __launch_bounds__(256)
k_rowmat_mfma(const float* __restrict__ src, const short* __restrict__ wfrag,
              const float* __restrict__ bias, float* __restrict__ dst, int rows) {
    __shared__ short8 wl[2048];          // 32 KB
    int tid = threadIdx.x;
    for (int e = tid; e < 2048; e += 256) wl[e] = ((const short8*)wfrag)[e];
    __syncthreads();
    int wv = tid >> 6, lane = tid & 63;
    int lrow = lane & 15;
    int lkb = (lane >> 4) << 3;          // k offset within 32-chunk
    float bv[8];
    #pragma unroll
    for (int nt = 0; nt < 8; ++nt) bv[nt] = BIAS ? bias[nt * 16 + lrow] : 0.f;

    for (int chunk = blockIdx.x * 64; chunk < rows; chunk += gridDim.x * 64) {
        int r = chunk + wv * 16 + lrow;
        short8 af[4];
        if (r < rows) {
            const float* rowp = src + (size_t)r * D;
            #pragma unroll
            for (int kk = 0; kk < 4; ++kk) {
                const float* p = rowp + kk * 32 + lkb;
                float4 v0 = *(const float4*)p;
                float4 v1 = *(const float4*)(p + 4);
                short8 a;
                a[0] = (short)f2bf(v0.x); a[1] = (short)f2bf(v0.y);
                a[2] = (short)f2bf(v0.z); a[3] = (short)f2bf(v0.w);
                a[4] = (short)f2bf(v1.x); a[5] = (short)f2bf(v1.y);
                a[6] = (short)f2bf(v1.z); a[7] = (short)f2bf(v1.w);
                af[kk] = a;
            }
        } else {
            #pragma unroll
            for (int kk = 0; kk < 4; ++kk) af[kk] = (short8)0;
        }
        f32x4 acc[8];
        #pragma unroll
        for (int nt = 0; nt < 8; ++nt) acc[nt] = (f32x4)0.f;
        #pragma unroll
        for (int nt = 0; nt < 8; ++nt) {
            #pragma unroll
            for (int kk = 0; kk < 4; ++kk)
                acc[nt] = __builtin_amdgcn_mfma_f32_16x16x32_bf16(
                              af[kk], wl[(nt * 4 + kk) * 64 + lane], acc[nt], 0, 0, 0);
        }
        int orow0 = chunk + wv * 16 + ((lane >> 4) << 2);
        #pragma unroll
        for (int nt = 0; nt < 8; ++nt) {
            int col = nt * 16 + lrow;
            #pragma unroll
            for (int reg = 0; reg < 4; ++reg) {
                int orow = orow0 + reg;
                if (orow < rows) {
                    float v = acc[nt][reg] + bv[nt];
                    if (RELU) v = fmaxf(v, 0.f);
                    dst[(size_t)orow * D + col] = v;
                }
            }
        }
    }
}

// ---------------- histogram ----------------
__global__ void k_hist(const int* __restrict__ idx, int n, int* __restrict__ cnt) {
    int i = blockIdx.x * blockDim.x + threadIdx.x;
    if (i < n) atomicAdd(&cnt[idx[i]], 1);
}

// ---------------- hierarchical exclusive scan ----------------
__global__ void k_scan_tile(const int* __restrict__ cnt, int n, int* __restrict__ starts,
                            int* __restrict__ tsum) {
    __shared__ int buf[SCAN_TILE];
    int tid = threadIdx.x;
    int i = blockIdx.x * SCAN_TILE + tid;
    int v = (i < n) ? cnt[i] : 0;
    buf[tid] = v;
    __syncthreads();
    for (int off = 1; off < SCAN_TILE; off <<= 1) {
        int t = (tid >= off) ? buf[tid - off] : 0;
        __syncthreads();
        buf[tid] += t;
        __syncthreads();
    }
    if (i < n) starts[i] = buf[tid] - v;
    if (tid == SCAN_TILE - 1) tsum[blockIdx.x] = buf[tid];
}

__global__ void k_scan_tsum(int* __restrict__ tsum, int ntiles, int* __restrict__ starts, int n) {
    __shared__ int buf[SCAN_TILE];
    int tid = threadIdx.x;
    int v = (tid < ntiles) ? tsum[tid] : 0;
    buf[tid] = v;
    __syncthreads();
    for (int off = 1; off < SCAN_TILE; off <<= 1) {
        int t = (tid >= off) ? buf[tid - off] : 0;
        __syncthreads();
        buf[tid] += t;
        __syncthreads();
    }
    if (tid < ntiles) tsum[tid] = buf[tid] - v;
    if (tid == SCAN_TILE - 1) starts[n] = buf[tid];
}

__global__ void k_scan_add(int* __restrict__ starts, int n, const int* __restrict__ tsum) {
    int i = blockIdx.x * blockDim.x + threadIdx.x;
    if (i < n) starts[i] += tsum[i >> 10];
}

// ---------------- mapper CSR fill: store batch[i] directly ----------------
__global__ void k_fill_m(const int* __restrict__ mapper, const int* __restrict__ batch,
                         const int* __restrict__ starts, int* __restrict__ cnt,
                         int* __restrict__ mvals) {
    int i = blockIdx.x * blockDim.x + threadIdx.x;
    if (i >= N_FRAG_NODES) return;
    int k = mapper[i];
    int pos = atomicSub(&cnt[k], 1) - 1;
    mvals[starts[k] + pos] = batch[i];
}

// ---------------- dinv[c] = rsqrt(indeg + 1) ----------------
__global__ void k_dinv(const int* __restrict__ cstart, float* __restrict__ dinv) {
    int c = blockIdx.x * blockDim.x + threadIdx.x;
    if (c >= N_FRAG_NODES) return;
    float deg = (float)(cstart[c + 1] - cstart[c] + 1);
    dinv[c] = rsqrtf(deg);
}

// ---------------- edge CSR fill: store packed (pw row, dinv[src]) ----------------
__global__ void k_fill_e(const int* __restrict__ erow, const int* __restrict__ ecol,
                         const int* __restrict__ mapper, const float* __restrict__ dinv,
                         const int* __restrict__ starts, int* __restrict__ cnt,
                         int2* __restrict__ erecs) {
    int i = blockIdx.x * blockDim.x + threadIdx.x;
    if (i >= NEDGE) return;
    int c = ecol[i], r = erow[i];
    int pos = atomicSub(&cnt[c], 1) - 1;
    int2 rec;
    rec.x = mapper[r];
    rec.y = __float_as_int(dinv[r]);
    erecs[starts[c] + pos] = rec;
}

// ---------------- pooled[n] = x[n] + mean_t fragu[mvals[t]]  (32-lane group per n) ----------------
__global__ void k_pool_csr(const float* __restrict__ x, const float* __restrict__ fragu,
                           const int* __restrict__ mstart, const int* __restrict__ mvals,
                           float* __restrict__ pooled) {
    int g = threadIdx.x >> 5, lane = threadIdx.x & 31;
    int n = blockIdx.x * 8 + g;
    if (n >= N_NODES) return;
    int s = mstart[n], e = mstart[n + 1];
    float4 out = {0.f, 0.f, 0.f, 0.f};
    if (e > s) {
        const float4* f4 = (const float4*)fragu;
        float4 sum = {0.f, 0.f, 0.f, 0.f};
        for (int t = s; t < e; ++t) {
            int b = mvals[t];
            float4 v = f4[(size_t)b * DV + lane];
            sum.x += v.x; sum.y += v.y; sum.z += v.z; sum.w += v.w;
        }
        float inv = 1.f / (float)(e - s);
        float4 xv = ((const float4*)x)[(size_t)n * DV + lane];
        out.x = xv.x + sum.x * inv; out.y = xv.y + sum.y * inv;
        out.z = xv.z + sum.z * inv; out.w = xv.w + sum.w * inv;
    }
    ((float4*)pooled)[(size_t)n * DV + lane] = out;
}

// ---------------- GCN gather (32-lane group per target node, float4, packed recs) ----------------
__global__ void k_gcn_gather(const int* __restrict__ mapper, const int* __restrict__ cstart,
                             const int2* __restrict__ erecs, const float* __restrict__ pw,
                             const float* __restrict__ dinv, const float* __restrict__ bgcn,
                             float* __restrict__ xout) {
    int g = threadIdx.x >> 5, lane = threadIdx.x & 31;
    int c = blockIdx.x * 8 + g;
    if (c >= N_FRAG_NODES) return;
    const float4* pw4 = (const float4*)pw;
    int s = cstart[c], e = cstart[c + 1];
    float4 acc = {0.f, 0.f, 0.f, 0.f};
    for (int t = s; t < e; ++t) {
        int2 rec = erecs[t];
        float w = __int_as_float(rec.y);
        float4 v = pw4[(size_t)rec.x * DV + lane];
        acc.x = fmaf(v.x, w, acc.x); acc.y = fmaf(v.y, w, acc.y);
        acc.z = fmaf(v.z, w, acc.z); acc.w = fmaf(v.w, w, acc.w);
    }
    float dc = dinv[c];
    float dc2 = dc * dc;
    float4 self = pw4[(size_t)mapper[c] * DV + lane];
    float4 bg = ((const float4*)bgcn)[lane];
    float4 o;
    o.x = fmaf(acc.x, dc, fmaf(self.x, dc2, bg.x));
    o.y = fmaf(acc.y, dc, fmaf(self.y, dc2, bg.y));
    o.z = fmaf(acc.z, dc, fmaf(self.z, dc2, bg.z));
    o.w = fmaf(acc.w, dc, fmaf(self.w, dc2, bg.w));
    ((float4*)xout)[(size_t)c * DV + lane] = o;
}

// ---------------- fragment_x[b] = mean_{j in seg(b)} xout[j]  (32-lane group per b) ----------------
__global__ void k_frag_x(const float* __restrict__ xout, const int* __restrict__ startb,
                         float* __restrict__ fout) {
    int g = threadIdx.x >> 5, lane = threadIdx.x & 31;
    int b = blockIdx.x * 8 + g;
    if (b >= N_FRAGS) return;
    const float4* x4 = (const float4*)xout;
    int s = startb[b], e = startb[b + 1];
    float4 sum = {0.f, 0.f, 0.f, 0.f};
    for (int j = s; j < e; ++j) {
        float4 v = x4[(size_t)j * DV + lane];
        sum.x += v.x; sum.y += v.y; sum.z += v.z; sum.w += v.w;
    }
    float4 r = {0.f, 0.f, 0.f, 0.f};
    if (e > s) {
        float inv = 1.f / (float)(e - s);
        r.x = sum.x * inv; r.y = sum.y * inv; r.z = sum.z * inv; r.w = sum.w * inv;
    }
    ((float4*)fout)[(size_t)b * DV + lane] = r;
}

static inline void run_scan(const int* cnt, int n, int* starts, int* tsum, hipStream_t stream) {
    int ntiles = (n + SCAN_TILE - 1) / SCAN_TILE;      // <= 1024
    k_scan_tile<<<ntiles, SCAN_TILE, 0, stream>>>(cnt, n, starts, tsum);
    k_scan_tsum<<<1, SCAN_TILE, 0, stream>>>(tsum, ntiles, starts, n);
    k_scan_add<<<(n + 255) / 256, 256, 0, stream>>>(starts, n, tsum);
}

extern "C" void kernel_launch(void* const* d_in, const int* in_sizes, int n_in,
                              void* d_out, int out_size, void* d_ws, size_t ws_size,
                              hipStream_t stream) {
    const float* x      = (const float*)d_in[0];         // f32 [N_NODES, D]
    const int*   mapper = (const int*)d_in[1];
    const int*   batch  = (const int*)d_in[2];
    const int*   erow   = (const int*)d_in[3];           // edge_index[0] (source)
    const int*   ecol   = erow + NEDGE;                  // edge_index[1] (target)
    const float* W_u    = (const float*)d_in[4];
    const float* b_u    = (const float*)d_in[5];
    const float* W_gcn  = (const float*)d_in[6];
    const float* b_gcn  = (const float*)d_in[7];

    float* fout = (float*)d_out;                         // f32 [N_FRAGS, D]
    float* xout = fout + (size_t)N_FRAGS * D;            // f32 [N_FRAG_NODES, D]

    // ---- workspace layout (~108 MB; 16B alignment maintained) ----
    short* wfragU = (short*)d_ws;                        // 2048 short8 = 32 KB
    short* wfragG = wfragU + 16384;                      // 32 KB
    int2*  erecs  = (int2*)(wfragG + 16384);             // 1,200,000 int2 (9.6 MB)
    float* frag   = (float*)(erecs + NEDGE);             // 3,840,000 f32  (-> fragu in place)
    float* pooled = frag + (size_t)N_FRAGS * D;          // 19,200,000 f32 (-> pw in place)
    float* dinv   = pooled + (size_t)N_NODES * D;        // 300,000 f32
    int*   startb = (int*)(dinv + N_FRAG_NODES);         // 30,001
    int*   mstart = startb + (N_FRAGS + 1);              // 150,001
    int*   cstart = mstart + (N_NODES + 1);              // 300,001
    int*   mcnt   = cstart + (N_FRAG_NODES + 1);         // 150,000  (memset 0)
    int*   ccnt   = mcnt + N_NODES;                      // 300,000  (memset 0)
    int*   mvals  = ccnt + N_FRAG_NODES;                 // 300,000
    int*   tsum   = mvals + N_FRAG_NODES;                // 1,024

    hipMemsetAsync(mcnt, 0, (size_t)(N_NODES + N_FRAG_NODES) * sizeof(int), stream);

    // W fragment tables (no deps on anything else)
    k_build_wfrag<<<1, 256, 0, stream>>>(W_u, wfragU);
    k_build_wfrag<<<1, 256, 0, stream>>>(W_gcn, wfragG);

    // fragment means + MLP
    k_starts<<<(N_FRAGS + 256) / 256, 256, 0, stream>>>(batch, startb);
    k_frag_mean<<<(N_FRAGS + 7) / 8, 256, 0, stream>>>(x, mapper, startb, frag);
    k_rowmat_mfma<true, true><<<469, 256, 0, stream>>>(frag, wfragU, b_u, frag, N_FRAGS);

    // mapper CSR (values = batch[j])
    k_hist<<<(N_FRAG_NODES + 255) / 256, 256, 0, stream>>>(mapper, N_FRAG_NODES, mcnt);
    run_scan(mcnt, N_NODES, mstart, tsum, stream);
    k_fill_m<<<(N_FRAG_NODES + 255) / 256, 256, 0, stream>>>(mapper, batch, mstart, mcnt, mvals);

    // node pooling + W_gcn
    k_pool_csr<<<(N_NODES + 7) / 8, 256, 0, stream>>>(x, frag, mstart, mvals, pooled);
    k_rowmat_mfma<false, false><<<1024, 256, 0, stream>>>(pooled, wfragG, nullptr, pooled, N_NODES);

    // edge CSR (packed (mapper[src], dinv[src]) records, keyed by target)
    k_hist<<<(NEDGE + 255) / 256, 256, 0, stream>>>(ecol, NEDGE, ccnt);
    run_scan(ccnt, N_FRAG_NODES, cstart, tsum, stream);
    k_dinv<<<(N_FRAG_NODES + 255) / 256, 256, 0, stream>>>(cstart, dinv);
    k_fill_e<<<(NEDGE + 255) / 256, 256, 0, stream>>>(erow, ecol, mapper, dinv, cstart, ccnt, erecs);

    // GCN aggregation (gather) -> f32 x_out
    k_gcn_gather<<<(N_FRAG_NODES + 7) / 8, 256, 0, stream>>>(mapper, cstart, erecs,
                                                             pooled, dinv, b_gcn, xout);
    // fragment mean of x_out
    k_frag_x<<<(N_FRAGS + 7) / 8, 256, 0, stream>>>(xout, startb, fout);
}

// Round 8
// 430.374 us; speedup vs baseline: 4.4513x; 1.0910x over previous
//
#include <hip/hip_runtime.h>
#include <hip/hip_bf16.h>

#define N_NODES      150000
#define N_FRAG_NODES 300000
#define N_FRAGS      30000
#define NEDGE        1200000
#define D            128
#define DV           32          // D/4 float4s per row
#define DU           32          // D/4 ushort4s per bf16 row
#define SCAN_TILE    1024

typedef __attribute__((ext_vector_type(8))) short short8;
typedef __attribute__((ext_vector_type(4))) float f32x4;

__device__ __forceinline__ unsigned short f2bf(float f) {
    unsigned u = __float_as_uint(f);
    u = (u + 0x7FFFu + ((u >> 16) & 1u)) >> 16;   // RNE
    return (unsigned short)u;
}
__device__ __forceinline__ float bf2f(unsigned short u) {
    return __uint_as_float((unsigned)u << 16);
}

// ---------------- segment starts of sorted batch ----------------
__global__ void k_starts(const int* __restrict__ batch, int* __restrict__ startb) {
    int b = blockIdx.x * blockDim.x + threadIdx.x;
    if (b > N_FRAGS) return;
    int lo = 0, hi = N_FRAG_NODES;
    while (lo < hi) { int mid = (lo + hi) >> 1; if (batch[mid] < b) lo = mid + 1; else hi = mid; }
    startb[b] = lo;
}

// ---------------- frag16[b] = bf16( mean_{j in seg(b)} x[mapper[j]] ) ----------------
__global__ void k_frag_mean(const float* __restrict__ x, const int* __restrict__ mapper,
                            const int* __restrict__ startb, ushort4* __restrict__ frag16) {
    int g = threadIdx.x >> 5, lane = threadIdx.x & 31;
    int b = blockIdx.x * 8 + g;
    if (b >= N_FRAGS) return;
    const float4* x4 = (const float4*)x;
    int s = startb[b], e = startb[b + 1];
    float4 sum = {0.f, 0.f, 0.f, 0.f};
    for (int j = s; j < e; ++j) {
        int m = mapper[j];
        float4 v = x4[(size_t)m * DV + lane];
        sum.x += v.x; sum.y += v.y; sum.z += v.z; sum.w += v.w;
    }
    float c = (float)(e - s); if (c < 1.f) c = 1.f;
    float inv = 1.f / c;
    ushort4 r = {f2bf(sum.x * inv), f2bf(sum.y * inv), f2bf(sum.z * inv), f2bf(sum.w * inv)};
    frag16[(size_t)b * DU + lane] = r;
}

// ---------------- build MFMA B-fragment table from W[128][128] f32 ----------------
// entry e = (nt*4 + kk)*64 + lane; 8 bf16: W[kk*32 + (lane>>4)*8 + j][nt*16 + (lane&15)]
__global__ void k_build_wfrag(const float* __restrict__ W, short* __restrict__ wfrag) {
    int t = threadIdx.x;
    for (int e = t; e < 2048; e += 256) {
        int nt = e >> 8;
        int kk = (e >> 6) & 3;
        int lane = e & 63;
        int col = nt * 16 + (lane & 15);
        int kb = kk * 32 + ((lane >> 4) << 3);
        short8 v;
        #pragma unroll
        for (int j = 0; j < 8; ++j) v[j] = (short)f2bf(W[(kb + j) * D + col]);
        ((short8*)wfrag)[e] = v;
    }
}

// ---------------- dst16[r] = bf16( act(src16[r] @ W + b) ) via MFMA; in-place safe ----------------
template <bool RELU, bool BIAS>
__global__ void __launch_bounds__(256)
k_rowmat_mfma(const unsigned short* __restrict__ src16, const short* __restrict__ wfrag,
              const float* __restrict__ bias, unsigned short* __restrict__ dst16, int rows) {
    __shared__ short8 wl[2048];          // 32 KB
    int tid = threadIdx.x;
    for (int e = tid; e < 2048; e += 256) wl[e] = ((const short8*)wfrag)[e];
    __syncthreads();
    int wv = tid >> 6, lane = tid & 63;
    int lrow = lane & 15;
    int lk8 = (lane >> 4);               // which short8 within a 32-chunk
    float bv[8];
    #pragma unroll
    for (int nt = 0; nt < 8; ++nt) bv[nt] = BIAS ? bias[nt * 16 + lrow] : 0.f;

    int chunk = blockIdx.x * 64;
    {
        int r = chunk + wv * 16 + lrow;
        short8 af[4];
        if (r < rows) {
            const short8* rowp = (const short8*)(src16 + (size_t)r * D);
            #pragma unroll
            for (int kk = 0; kk < 4; ++kk) af[kk] = rowp[kk * 4 + lk8];
        } else {
            #pragma unroll
            for (int kk = 0; kk < 4; ++kk) af[kk] = (short8)0;
        }
        f32x4 acc[8];
        #pragma unroll
        for (int nt = 0; nt < 8; ++nt) acc[nt] = (f32x4)0.f;
        #pragma unroll
        for (int nt = 0; nt < 8; ++nt) {
            #pragma unroll
            for (int kk = 0; kk < 4; ++kk)
                acc[nt] = __builtin_amdgcn_mfma_f32_16x16x32_bf16(
                              af[kk], wl[(nt * 4 + kk) * 64 + lane], acc[nt], 0, 0, 0);
        }
        int orow0 = chunk + wv * 16 + ((lane >> 4) << 2);
        #pragma unroll
        for (int nt = 0; nt < 8; ++nt) {
            int col = nt * 16 + lrow;
            #pragma unroll
            for (int reg = 0; reg < 4; ++reg) {
                int orow = orow0 + reg;
                if (orow < rows) {
                    float v = acc[nt][reg] + bv[nt];
                    if (RELU) v = fmaxf(v, 0.f);
                    dst16[(size_t)orow * D + col] = f2bf(v);
                }
            }
        }
    }
}

// ---------------- histogram ----------------
__global__ void k_hist(const int* __restrict__ idx, int n, int* __restrict__ cnt) {
    int i = blockIdx.x * blockDim.x + threadIdx.x;
    if (i < n) atomicAdd(&cnt[idx[i]], 1);
}

// ---------------- hierarchical exclusive scan ----------------
__global__ void k_scan_tile(const int* __restrict__ cnt, int n, int* __restrict__ starts,
                            int* __restrict__ tsum) {
    __shared__ int buf[SCAN_TILE];
    int tid = threadIdx.x;
    int i = blockIdx.x * SCAN_TILE + tid;
    int v = (i < n) ? cnt[i] : 0;
    buf[tid] = v;
    __syncthreads();
    for (int off = 1; off < SCAN_TILE; off <<= 1) {
        int t = (tid >= off) ? buf[tid - off] : 0;
        __syncthreads();
        buf[tid] += t;
        __syncthreads();
    }
    if (i < n) starts[i] = buf[tid] - v;
    if (tid == SCAN_TILE - 1) tsum[blockIdx.x] = buf[tid];
}

__global__ void k_scan_tsum(int* __restrict__ tsum, int ntiles, int* __restrict__ starts, int n) {
    __shared__ int buf[SCAN_TILE];
    int tid = threadIdx.x;
    int v = (tid < ntiles) ? tsum[tid] : 0;
    buf[tid] = v;
    __syncthreads();
    for (int off = 1; off < SCAN_TILE; off <<= 1) {
        int t = (tid >= off) ? buf[tid - off] : 0;
        __syncthreads();
        buf[tid] += t;
        __syncthreads();
    }
    if (tid < ntiles) tsum[tid] = buf[tid] - v;
    if (tid == SCAN_TILE - 1) starts[n] = buf[tid];
}

__global__ void k_scan_add(int* __restrict__ starts, int n, const int* __restrict__ tsum) {
    int i = blockIdx.x * blockDim.x + threadIdx.x;
    if (i < n) starts[i] += tsum[i >> 10];
}

// ---------------- mapper CSR fill: store batch[i] directly ----------------
__global__ void k_fill_m(const int* __restrict__ mapper, const int* __restrict__ batch,
                         const int* __restrict__ starts, int* __restrict__ cnt,
                         int* __restrict__ mvals) {
    int i = blockIdx.x * blockDim.x + threadIdx.x;
    if (i >= N_FRAG_NODES) return;
    int k = mapper[i];
    int pos = atomicSub(&cnt[k], 1) - 1;
    mvals[starts[k] + pos] = batch[i];
}

// ---------------- dinv[c] = rsqrt(indeg + 1) ----------------
__global__ void k_dinv(const int* __restrict__ cstart, float* __restrict__ dinv) {
    int c = blockIdx.x * blockDim.x + threadIdx.x;
    if (c >= N_FRAG_NODES) return;
    float deg = (float)(cstart[c + 1] - cstart[c] + 1);
    dinv[c] = rsqrtf(deg);
}

// ---------------- edge CSR fill: store packed (pw row, dinv[src]) ----------------
__global__ void k_fill_e(const int* __restrict__ erow, const int* __restrict__ ecol,
                         const int* __restrict__ mapper, const float* __restrict__ dinv,
                         const int* __restrict__ starts, int* __restrict__ cnt,
                         int2* __restrict__ erecs) {
    int i = blockIdx.x * blockDim.x + threadIdx.x;
    if (i >= NEDGE) return;
    int c = ecol[i], r = erow[i];
    int pos = atomicSub(&cnt[c], 1) - 1;
    int2 rec;
    rec.x = mapper[r];
    rec.y = __float_as_int(dinv[r]);
    erecs[starts[c] + pos] = rec;
}

// ---------------- pooled16[n] = bf16( x[n] + mean_t fragu16[mvals[t]] ) ----------------
__global__ void k_pool_csr(const float* __restrict__ x, const ushort4* __restrict__ fragu16,
                           const int* __restrict__ mstart, const int* __restrict__ mvals,
                           ushort4* __restrict__ pooled16) {
    int g = threadIdx.x >> 5, lane = threadIdx.x & 31;
    int n = blockIdx.x * 8 + g;
    if (n >= N_NODES) return;
    int s = mstart[n], e = mstart[n + 1];
    ushort4 out = {0, 0, 0, 0};                      // bf16 zero
    if (e > s) {
        float4 sum = {0.f, 0.f, 0.f, 0.f};
        for (int t = s; t < e; ++t) {
            int b = mvals[t];
            ushort4 u = fragu16[(size_t)b * DU + lane];
            sum.x += bf2f(u.x); sum.y += bf2f(u.y); sum.z += bf2f(u.z); sum.w += bf2f(u.w);
        }
        float inv = 1.f / (float)(e - s);
        float4 xv = ((const float4*)x)[(size_t)n * DV + lane];
        out.x = f2bf(xv.x + sum.x * inv); out.y = f2bf(xv.y + sum.y * inv);
        out.z = f2bf(xv.z + sum.z * inv); out.w = f2bf(xv.w + sum.w * inv);
    }
    pooled16[(size_t)n * DU + lane] = out;
}

// ---------------- GCN gather (bf16 pw rows) -> f32 x_out ----------------
__global__ void k_gcn_gather(const int* __restrict__ mapper, const int* __restrict__ cstart,
                             const int2* __restrict__ erecs, const ushort4* __restrict__ pw16,
                             const float* __restrict__ dinv, const float* __restrict__ bgcn,
                             float* __restrict__ xout) {
    int g = threadIdx.x >> 5, lane = threadIdx.x & 31;
    int c = blockIdx.x * 8 + g;
    if (c >= N_FRAG_NODES) return;
    int s = cstart[c], e = cstart[c + 1];
    float4 acc = {0.f, 0.f, 0.f, 0.f};
    for (int t = s; t < e; ++t) {
        int2 rec = erecs[t];
        float w = __int_as_float(rec.y);
        ushort4 u = pw16[(size_t)rec.x * DU + lane];
        acc.x = fmaf(bf2f(u.x), w, acc.x); acc.y = fmaf(bf2f(u.y), w, acc.y);
        acc.z = fmaf(bf2f(u.z), w, acc.z); acc.w = fmaf(bf2f(u.w), w, acc.w);
    }
    float dc = dinv[c];
    float dc2 = dc * dc;
    ushort4 su = pw16[(size_t)mapper[c] * DU + lane];
    float4 bg = ((const float4*)bgcn)[lane];
    float4 o;
    o.x = fmaf(acc.x, dc, fmaf(bf2f(su.x), dc2, bg.x));
    o.y = fmaf(acc.y, dc, fmaf(bf2f(su.y), dc2, bg.y));
    o.z = fmaf(acc.z, dc, fmaf(bf2f(su.z), dc2, bg.z));
    o.w = fmaf(acc.w, dc, fmaf(bf2f(su.w), dc2, bg.w));
    ((float4*)xout)[(size_t)c * DV + lane] = o;
}

// ---------------- fragment_x[b] = mean_{j in seg(b)} xout[j] ----------------
__global__ void k_frag_x(const float* __restrict__ xout, const int* __restrict__ startb,
                         float* __restrict__ fout) {
    int g = threadIdx.x >> 5, lane = threadIdx.x & 31;
    int b = blockIdx.x * 8 + g;
    if (b >= N_FRAGS) return;
    const float4* x4 = (const float4*)xout;
    int s = startb[b], e = startb[b + 1];
    float4 sum = {0.f, 0.f, 0.f, 0.f};
    for (int j = s; j < e; ++j) {
        float4 v = x4[(size_t)j * DV + lane];
        sum.x += v.x; sum.y += v.y; sum.z += v.z; sum.w += v.w;
    }
    float4 r = {0.f, 0.f, 0.f, 0.f};
    if (e > s) {
        float inv = 1.f / (float)(e - s);
        r.x = sum.x * inv; r.y = sum.y * inv; r.z = sum.z * inv; r.w = sum.w * inv;
    }
    ((float4*)fout)[(size_t)b * DV + lane] = r;
}

static inline void run_scan(const int* cnt, int n, int* starts, int* tsum, hipStream_t stream) {
    int ntiles = (n + SCAN_TILE - 1) / SCAN_TILE;      // <= 1024
    k_scan_tile<<<ntiles, SCAN_TILE, 0, stream>>>(cnt, n, starts, tsum);
    k_scan_tsum<<<1, SCAN_TILE, 0, stream>>>(tsum, ntiles, starts, n);
    k_scan_add<<<(n + 255) / 256, 256, 0, stream>>>(starts, n, tsum);
}

extern "C" void kernel_launch(void* const* d_in, const int* in_sizes, int n_in,
                              void* d_out, int out_size, void* d_ws, size_t ws_size,
                              hipStream_t stream) {
    const float* x      = (const float*)d_in[0];         // f32 [N_NODES, D]
    const int*   mapper = (const int*)d_in[1];
    const int*   batch  = (const int*)d_in[2];
    const int*   erow   = (const int*)d_in[3];           // edge_index[0] (source)
    const int*   ecol   = erow + NEDGE;                  // edge_index[1] (target)
    const float* W_u    = (const float*)d_in[4];
    const float* b_u    = (const float*)d_in[5];
    const float* W_gcn  = (const float*)d_in[6];
    const float* b_gcn  = (const float*)d_in[7];

    float* fout = (float*)d_out;                         // f32 [N_FRAGS, D]
    float* xout = fout + (size_t)N_FRAGS * D;            // f32 [N_FRAG_NODES, D]

    // ---- workspace layout (~65 MB; 16B alignment maintained) ----
    short*  wfragU   = (short*)d_ws;                     // 32 KB
    short*  wfragG   = wfragU + 16384;                   // 32 KB
    int2*   erecs    = (int2*)(wfragG + 16384);          // 1,200,000 int2 (9.6 MB)
    unsigned short* frag16   = (unsigned short*)(erecs + NEDGE);        // 30000*128 bf16 (7.68 MB) -> fragu16 in place
    unsigned short* pooled16 = frag16 + (size_t)N_FRAGS * D;            // 150000*128 bf16 (38.4 MB) -> pw16 in place
    float*  dinv   = (float*)(pooled16 + (size_t)N_NODES * D);          // 300,000 f32
    int*    startb = (int*)(dinv + N_FRAG_NODES);        // 30,001
    int*    mstart = startb + (N_FRAGS + 1);             // 150,001
    int*    cstart = mstart + (N_NODES + 1);             // 300,001
    int*    mcnt   = cstart + (N_FRAG_NODES + 1);        // 150,000  (memset 0)
    int*    ccnt   = mcnt + N_NODES;                     // 300,000  (memset 0)
    int*    mvals  = ccnt + N_FRAG_NODES;                // 300,000
    int*    tsum   = mvals + N_FRAG_NODES;               // 1,024

    hipMemsetAsync(mcnt, 0, (size_t)(N_NODES + N_FRAG_NODES) * sizeof(int), stream);

    // W fragment tables
    k_build_wfrag<<<1, 256, 0, stream>>>(W_u, wfragU);
    k_build_wfrag<<<1, 256, 0, stream>>>(W_gcn, wfragG);

    // fragment means + MLP (bf16 pipeline)
    k_starts<<<(N_FRAGS + 256) / 256, 256, 0, stream>>>(batch, startb);
    k_frag_mean<<<(N_FRAGS + 7) / 8, 256, 0, stream>>>(x, mapper, startb, (ushort4*)frag16);
    k_rowmat_mfma<true, true><<<(N_FRAGS + 63) / 64, 256, 0, stream>>>(
        frag16, wfragU, b_u, frag16, N_FRAGS);                           // fragu16 in place

    // mapper CSR (values = batch[j])
    k_hist<<<(N_FRAG_NODES + 255) / 256, 256, 0, stream>>>(mapper, N_FRAG_NODES, mcnt);
    run_scan(mcnt, N_NODES, mstart, tsum, stream);
    k_fill_m<<<(N_FRAG_NODES + 255) / 256, 256, 0, stream>>>(mapper, batch, mstart, mcnt, mvals);

    // node pooling + W_gcn (bf16 in/out)
    k_pool_csr<<<(N_NODES + 7) / 8, 256, 0, stream>>>(x, (const ushort4*)frag16,
                                                      mstart, mvals, (ushort4*)pooled16);
    k_rowmat_mfma<false, false><<<(N_NODES + 63) / 64, 256, 0, stream>>>(
        pooled16, wfragG, nullptr, pooled16, N_NODES);                   // pw16 in place

    // edge CSR (packed (mapper[src], dinv[src]) records, keyed by target)
    k_hist<<<(NEDGE + 255) / 256, 256, 0, stream>>>(ecol, NEDGE, ccnt);
    run_scan(ccnt, N_FRAG_NODES, cstart, tsum, stream);
    k_dinv<<<(N_FRAG_NODES + 255) / 256, 256, 0, stream>>>(cstart, dinv);
    k_fill_e<<<(NEDGE + 255) / 256, 256, 0, stream>>>(erow, ecol, mapper, dinv, cstart, ccnt, erecs);

    // GCN aggregation (gather, bf16 rows) -> f32 x_out
    k_gcn_gather<<<(N_FRAG_NODES + 7) / 8, 256, 0, stream>>>(mapper, cstart, erecs,
                                                             (const ushort4*)pooled16,
                                                             dinv, b_gcn, xout);
    // fragment mean of x_out
    k_frag_x<<<(N_FRAGS + 7) / 8, 256, 0, stream>>>(xout, startb, fout);
}

// Round 9
// 366.922 us; speedup vs baseline: 5.2211x; 1.1729x over previous
//
#include <hip/hip_runtime.h>
#include <hip/hip_bf16.h>

#define N_NODES      150000
#define N_FRAG_NODES 300000
#define N_FRAGS      30000
#define NEDGE        1200000
#define NCNT         (N_NODES + N_FRAG_NODES)   // combined counter array length
#define D            128
#define DV           32          // float4s per f32 row
#define SCAN_TILE    1024

typedef __attribute__((ext_vector_type(8))) short short8;
typedef __attribute__((ext_vector_type(8))) unsigned short u16x8;
typedef __attribute__((ext_vector_type(4))) float f32x4;

__device__ __forceinline__ unsigned short f2bf(float f) {
    unsigned u = __float_as_uint(f);
    u = (u + 0x7FFFu + ((u >> 16) & 1u)) >> 16;   // RNE
    return (unsigned short)u;
}
__device__ __forceinline__ float bf2f(unsigned short u) {
    return __uint_as_float((unsigned)u << 16);
}

// ---------------- prep: both histograms + segment starts of sorted batch ----------------
__global__ void k_prep(const int* __restrict__ mapper, const int* __restrict__ batch,
                       const int* __restrict__ ecol, int* __restrict__ mcnt,
                       int* __restrict__ ccnt, int* __restrict__ startb) {
    int i = blockIdx.x * blockDim.x + threadIdx.x;
    if (i < NEDGE) atomicAdd(&ccnt[ecol[i]], 1);
    if (i < N_FRAG_NODES) atomicAdd(&mcnt[mapper[i]], 1);
    if (i <= N_FRAGS) {
        int lo = 0, hi = N_FRAG_NODES;
        while (lo < hi) { int mid = (lo + hi) >> 1; if (batch[mid] < i) lo = mid + 1; else hi = mid; }
        startb[i] = lo;
    }
}

// ---------------- combined hierarchical scan over [mcnt | ccnt] (450000) ----------------
__global__ void k_scan_tile(const int* __restrict__ cnt, int* __restrict__ combst,
                            int* __restrict__ tsum) {
    __shared__ int buf[SCAN_TILE];
    int tid = threadIdx.x;
    int i = blockIdx.x * SCAN_TILE + tid;
    int v = (i < NCNT) ? cnt[i] : 0;
    buf[tid] = v;
    __syncthreads();
    for (int off = 1; off < SCAN_TILE; off <<= 1) {
        int t = (tid >= off) ? buf[tid - off] : 0;
        __syncthreads();
        buf[tid] += t;
        __syncthreads();
    }
    if (i < NCNT) combst[i] = buf[tid] - v;
    if (tid == SCAN_TILE - 1) tsum[blockIdx.x] = buf[tid];
}

__global__ void k_scan_tsum(int* __restrict__ tsum, int ntiles,
                            int* __restrict__ mstart, int* __restrict__ cstart) {
    __shared__ int buf[SCAN_TILE];
    int tid = threadIdx.x;
    int v = (tid < ntiles) ? tsum[tid] : 0;
    buf[tid] = v;
    __syncthreads();
    for (int off = 1; off < SCAN_TILE; off <<= 1) {
        int t = (tid >= off) ? buf[tid - off] : 0;
        __syncthreads();
        buf[tid] += t;
        __syncthreads();
    }
    if (tid < ntiles) tsum[tid] = buf[tid] - v;
    if (tid == SCAN_TILE - 1) {
        mstart[N_NODES] = N_FRAG_NODES;                  // total of mapper counts
        cstart[N_FRAG_NODES] = buf[tid] - N_FRAG_NODES;  // = NEDGE
    }
}

__global__ void k_scan_add(const int* __restrict__ combst, const int* __restrict__ tsum,
                           int* __restrict__ mstart, int* __restrict__ cstart) {
    int i = blockIdx.x * blockDim.x + threadIdx.x;
    if (i >= NCNT) return;
    int v = combst[i] + tsum[i >> 10];
    if (i < N_NODES) mstart[i] = v;
    else cstart[i - N_NODES] = v - N_FRAG_NODES;
}

// ---------------- frag16[b] = bf16( mean_{j in seg(b)} x[mapper[j]] ) ----------------
__global__ void k_frag_mean(const float4* __restrict__ x4, const int* __restrict__ mapper,
                            const int* __restrict__ startb, ushort4* __restrict__ frag16) {
    int g = threadIdx.x >> 5, lane = threadIdx.x & 31;
    int b = blockIdx.x * 8 + g;
    if (b >= N_FRAGS) return;
    int s = startb[b], e = startb[b + 1];
    float4 sA = {0.f, 0.f, 0.f, 0.f}, sB = {0.f, 0.f, 0.f, 0.f};
    int j = s;
    for (; j + 2 <= e; j += 2) {
        int m0 = mapper[j], m1 = mapper[j + 1];
        float4 v0 = x4[(size_t)m0 * DV + lane];
        float4 v1 = x4[(size_t)m1 * DV + lane];
        sA.x += v0.x; sA.y += v0.y; sA.z += v0.z; sA.w += v0.w;
        sB.x += v1.x; sB.y += v1.y; sB.z += v1.z; sB.w += v1.w;
    }
    if (j < e) {
        int m0 = mapper[j];
        float4 v0 = x4[(size_t)m0 * DV + lane];
        sA.x += v0.x; sA.y += v0.y; sA.z += v0.z; sA.w += v0.w;
    }
    float c = (float)(e - s); if (c < 1.f) c = 1.f;
    float inv = 1.f / c;
    ushort4 r = {f2bf((sA.x + sB.x) * inv), f2bf((sA.y + sB.y) * inv),
                 f2bf((sA.z + sB.z) * inv), f2bf((sA.w + sB.w) * inv)};
    frag16[(size_t)b * DV + lane] = r;
}

// ---------------- build MFMA B-fragment table from W[128][128] f32 ----------------
__global__ void k_build_wfrag(const float* __restrict__ W, short* __restrict__ wfrag) {
    int t = threadIdx.x;
    for (int e = t; e < 2048; e += 256) {
        int nt = e >> 8;
        int kk = (e >> 6) & 3;
        int lane = e & 63;
        int col = nt * 16 + (lane & 15);
        int kb = kk * 32 + ((lane >> 4) << 3);
        short8 v;
        #pragma unroll
        for (int j = 0; j < 8; ++j) v[j] = (short)f2bf(W[(kb + j) * D + col]);
        ((short8*)wfrag)[e] = v;
    }
}

// ---------------- dst16[r] = bf16( act(src16[r] @ W + b) ) via MFMA; in-place safe ----------------
template <bool RELU, bool BIAS>
__global__ void __launch_bounds__(256)
k_rowmat_mfma(const unsigned short* __restrict__ src16, const short* __restrict__ wfrag,
              const float* __restrict__ bias, unsigned short* __restrict__ dst16, int rows) {
    __shared__ short8 wl[2048];          // 32 KB
    int tid = threadIdx.x;
    for (int e = tid; e < 2048; e += 256) wl[e] = ((const short8*)wfrag)[e];
    __syncthreads();
    int wv = tid >> 6, lane = tid & 63;
    int lrow = lane & 15;
    int lk8 = (lane >> 4);               // which short8 within a 32-chunk
    float bv[8];
    #pragma unroll
    for (int nt = 0; nt < 8; ++nt) bv[nt] = BIAS ? bias[nt * 16 + lrow] : 0.f;

    int chunk = blockIdx.x * 64;
    {
        int r = chunk + wv * 16 + lrow;
        short8 af[4];
        if (r < rows) {
            const short8* rowp = (const short8*)(src16 + (size_t)r * D);
            #pragma unroll
            for (int kk = 0; kk < 4; ++kk) af[kk] = rowp[kk * 4 + lk8];
        } else {
            #pragma unroll
            for (int kk = 0; kk < 4; ++kk) af[kk] = (short8)0;
        }
        f32x4 acc[8];
        #pragma unroll
        for (int nt = 0; nt < 8; ++nt) acc[nt] = (f32x4)0.f;
        #pragma unroll
        for (int nt = 0; nt < 8; ++nt) {
            #pragma unroll
            for (int kk = 0; kk < 4; ++kk)
                acc[nt] = __builtin_amdgcn_mfma_f32_16x16x32_bf16(
                              af[kk], wl[(nt * 4 + kk) * 64 + lane], acc[nt], 0, 0, 0);
        }
        int orow0 = chunk + wv * 16 + ((lane >> 4) << 2);
        #pragma unroll
        for (int nt = 0; nt < 8; ++nt) {
            int col = nt * 16 + lrow;
            #pragma unroll
            for (int reg = 0; reg < 4; ++reg) {
                int orow = orow0 + reg;
                if (orow < rows) {
                    float v = acc[nt][reg] + bv[nt];
                    if (RELU) v = fmaxf(v, 0.f);
                    dst16[(size_t)orow * D + col] = f2bf(v);
                }
            }
        }
    }
}

// ---------------- mapper CSR fill: store batch[i] directly ----------------
__global__ void k_fill_m(const int* __restrict__ mapper, const int* __restrict__ batch,
                         const int* __restrict__ mstart, int* __restrict__ mcnt,
                         int* __restrict__ mvals) {
    int i = blockIdx.x * blockDim.x + threadIdx.x;
    if (i >= N_FRAG_NODES) return;
    int k = mapper[i];
    int pos = atomicSub(&mcnt[k], 1) - 1;
    mvals[mstart[k] + pos] = batch[i];
}

// ---------------- edge CSR fill: packed (pw row, rsqrt(indeg(src)+1)) ----------------
__global__ void k_fill_e(const int* __restrict__ erow, const int* __restrict__ ecol,
                         const int* __restrict__ mapper, const int* __restrict__ cstart,
                         int* __restrict__ ccnt, int2* __restrict__ erecs) {
    int i = blockIdx.x * blockDim.x + threadIdx.x;
    if (i >= NEDGE) return;
    int c = ecol[i], r = erow[i];
    int pos = atomicSub(&ccnt[c], 1) - 1;
    float w = rsqrtf((float)(cstart[r + 1] - cstart[r] + 1));
    int2 rec;
    rec.x = mapper[r];
    rec.y = __float_as_int(w);
    erecs[cstart[c] + pos] = rec;
}

// ---------------- pooled16[n] = bf16( x[n] + mean_t fragu16[mvals[t]] )  (16-lane groups) ----------------
__global__ void k_pool_csr(const float4* __restrict__ x4, const u16x8* __restrict__ fragu8,
                           const int* __restrict__ mstart, const int* __restrict__ mvals,
                           u16x8* __restrict__ pooled8) {
    int g = threadIdx.x >> 4, lane = threadIdx.x & 15;
    int n = blockIdx.x * 16 + g;
    if (n >= N_NODES) return;
    int s = mstart[n], e = mstart[n + 1];
    u16x8 out = (u16x8)0;                // bf16 zeros
    if (e > s) {
        float accA[8], accB[8];
        #pragma unroll
        for (int j = 0; j < 8; ++j) { accA[j] = 0.f; accB[j] = 0.f; }
        int t = s;
        for (; t + 2 <= e; t += 2) {
            int b0 = mvals[t], b1 = mvals[t + 1];
            u16x8 u0 = fragu8[(size_t)b0 * 16 + lane];
            u16x8 u1 = fragu8[(size_t)b1 * 16 + lane];
            #pragma unroll
            for (int j = 0; j < 8; ++j) {
                accA[j] += bf2f(u0[j]);
                accB[j] += bf2f(u1[j]);
            }
        }
        if (t < e) {
            int b0 = mvals[t];
            u16x8 u0 = fragu8[(size_t)b0 * 16 + lane];
            #pragma unroll
            for (int j = 0; j < 8; ++j) accA[j] += bf2f(u0[j]);
        }
        float inv = 1.f / (float)(e - s);
        float4 xv0 = x4[(size_t)n * DV + lane * 2];
        float4 xv1 = x4[(size_t)n * DV + lane * 2 + 1];
        out[0] = f2bf(fmaf(accA[0] + accB[0], inv, xv0.x));
        out[1] = f2bf(fmaf(accA[1] + accB[1], inv, xv0.y));
        out[2] = f2bf(fmaf(accA[2] + accB[2], inv, xv0.z));
        out[3] = f2bf(fmaf(accA[3] + accB[3], inv, xv0.w));
        out[4] = f2bf(fmaf(accA[4] + accB[4], inv, xv1.x));
        out[5] = f2bf(fmaf(accA[5] + accB[5], inv, xv1.y));
        out[6] = f2bf(fmaf(accA[6] + accB[6], inv, xv1.z));
        out[7] = f2bf(fmaf(accA[7] + accB[7], inv, xv1.w));
    }
    pooled8[(size_t)n * 16 + lane] = out;
}

// ---------------- GCN gather (16-lane groups, ushort8, 2x unroll) -> f32 x_out ----------------
__global__ void k_gcn_gather(const int* __restrict__ mapper, const int* __restrict__ cstart,
                             const int2* __restrict__ erecs, const u16x8* __restrict__ pw8,
                             const float* __restrict__ bgcn, float4* __restrict__ xout4) {
    int g = threadIdx.x >> 4, lane = threadIdx.x & 15;
    int c = blockIdx.x * 16 + g;
    if (c >= N_FRAG_NODES) return;
    int s = cstart[c], e = cstart[c + 1];
    float dc = rsqrtf((float)(e - s + 1));
    float accA[8], accB[8];
    #pragma unroll
    for (int j = 0; j < 8; ++j) { accA[j] = 0.f; accB[j] = 0.f; }
    int t = s;
    for (; t + 2 <= e; t += 2) {
        int2 r0 = erecs[t];
        int2 r1 = erecs[t + 1];
        u16x8 u0 = pw8[(size_t)r0.x * 16 + lane];
        u16x8 u1 = pw8[(size_t)r1.x * 16 + lane];
        float w0 = __int_as_float(r0.y);
        float w1 = __int_as_float(r1.y);
        #pragma unroll
        for (int j = 0; j < 8; ++j) {
            accA[j] = fmaf(bf2f(u0[j]), w0, accA[j]);
            accB[j] = fmaf(bf2f(u1[j]), w1, accB[j]);
        }
    }
    if (t < e) {
        int2 r0 = erecs[t];
        u16x8 u0 = pw8[(size_t)r0.x * 16 + lane];
        float w0 = __int_as_float(r0.y);
        #pragma unroll
        for (int j = 0; j < 8; ++j) accA[j] = fmaf(bf2f(u0[j]), w0, accA[j]);
    }
    u16x8 su = pw8[(size_t)mapper[c] * 16 + lane];
    float dc2 = dc * dc;
    const float4* bg4 = (const float4*)bgcn;
    float4 b0 = bg4[lane * 2], b1 = bg4[lane * 2 + 1];
    float4 o0, o1;
    o0.x = fmaf(accA[0] + accB[0], dc, fmaf(bf2f(su[0]), dc2, b0.x));
    o0.y = fmaf(accA[1] + accB[1], dc, fmaf(bf2f(su[1]), dc2, b0.y));
    o0.z = fmaf(accA[2] + accB[2], dc, fmaf(bf2f(su[2]), dc2, b0.z));
    o0.w = fmaf(accA[3] + accB[3], dc, fmaf(bf2f(su[3]), dc2, b0.w));
    o1.x = fmaf(accA[4] + accB[4], dc, fmaf(bf2f(su[4]), dc2, b1.x));
    o1.y = fmaf(accA[5] + accB[5], dc, fmaf(bf2f(su[5]), dc2, b1.y));
    o1.z = fmaf(accA[6] + accB[6], dc, fmaf(bf2f(su[6]), dc2, b1.z));
    o1.w = fmaf(accA[7] + accB[7], dc, fmaf(bf2f(su[7]), dc2, b1.w));
    xout4[(size_t)c * DV + lane * 2] = o0;
    xout4[(size_t)c * DV + lane * 2 + 1] = o1;
}

// ---------------- fragment_x[b] = mean_{j in seg(b)} xout[j] ----------------
__global__ void k_frag_x(const float4* __restrict__ x4, const int* __restrict__ startb,
                         float4* __restrict__ fout4) {
    int g = threadIdx.x >> 5, lane = threadIdx.x & 31;
    int b = blockIdx.x * 8 + g;
    if (b >= N_FRAGS) return;
    int s = startb[b], e = startb[b + 1];
    float4 sA = {0.f, 0.f, 0.f, 0.f}, sB = {0.f, 0.f, 0.f, 0.f};
    int j = s;
    for (; j + 2 <= e; j += 2) {
        float4 v0 = x4[(size_t)j * DV + lane];
        float4 v1 = x4[(size_t)(j + 1) * DV + lane];
        sA.x += v0.x; sA.y += v0.y; sA.z += v0.z; sA.w += v0.w;
        sB.x += v1.x; sB.y += v1.y; sB.z += v1.z; sB.w += v1.w;
    }
    if (j < e) {
        float4 v0 = x4[(size_t)j * DV + lane];
        sA.x += v0.x; sA.y += v0.y; sA.z += v0.z; sA.w += v0.w;
    }
    float4 r = {0.f, 0.f, 0.f, 0.f};
    if (e > s) {
        float inv = 1.f / (float)(e - s);
        r.x = (sA.x + sB.x) * inv; r.y = (sA.y + sB.y) * inv;
        r.z = (sA.z + sB.z) * inv; r.w = (sA.w + sB.w) * inv;
    }
    fout4[(size_t)b * DV + lane] = r;
}

extern "C" void kernel_launch(void* const* d_in, const int* in_sizes, int n_in,
                              void* d_out, int out_size, void* d_ws, size_t ws_size,
                              hipStream_t stream) {
    const float* x      = (const float*)d_in[0];         // f32 [N_NODES, D]
    const int*   mapper = (const int*)d_in[1];
    const int*   batch  = (const int*)d_in[2];
    const int*   erow   = (const int*)d_in[3];           // edge_index[0] (source)
    const int*   ecol   = erow + NEDGE;                  // edge_index[1] (target)
    const float* W_u    = (const float*)d_in[4];
    const float* b_u    = (const float*)d_in[5];
    const float* W_gcn  = (const float*)d_in[6];
    const float* b_gcn  = (const float*)d_in[7];

    float* fout = (float*)d_out;                         // f32 [N_FRAGS, D]
    float* xout = fout + (size_t)N_FRAGS * D;            // f32 [N_FRAG_NODES, D]

    // ---- workspace layout (~63 MB; 16B alignment maintained) ----
    short*  wfragU   = (short*)d_ws;                     // 32 KB
    short*  wfragG   = wfragU + 16384;                   // 32 KB
    int2*   erecs    = (int2*)(wfragG + 16384);          // 1,200,000 int2 (9.6 MB)
    unsigned short* frag16   = (unsigned short*)(erecs + NEDGE);   // 30000*128 bf16 -> fragu16 in place
    unsigned short* pooled16 = frag16 + (size_t)N_FRAGS * D;       // 150000*128 bf16 -> pw16 in place
    int*    startb = (int*)(pooled16 + (size_t)N_NODES * D);       // 30,001
    int*    mstart = startb + (N_FRAGS + 1);             // 150,001
    int*    cstart = mstart + (N_NODES + 1);             // 300,001
    int*    mcnt   = cstart + (N_FRAG_NODES + 1);        // 150,000  (memset 0)
    int*    ccnt   = mcnt + N_NODES;                     // 300,000  (memset 0, contiguous after mcnt)
    int*    mvals  = ccnt + N_FRAG_NODES;                // 300,000
    int*    combst = mvals + N_FRAG_NODES;               // 450,000
    int*    tsum   = combst + NCNT;                      // 1,024

    hipMemsetAsync(mcnt, 0, (size_t)NCNT * sizeof(int), stream);

    // W fragment tables
    k_build_wfrag<<<1, 256, 0, stream>>>(W_u, wfragU);
    k_build_wfrag<<<1, 256, 0, stream>>>(W_gcn, wfragG);

    // histograms + batch segment starts
    k_prep<<<(NEDGE + 255) / 256, 256, 0, stream>>>(mapper, batch, ecol, mcnt, ccnt, startb);

    // combined scan of [mcnt | ccnt] -> mstart / cstart
    int ntiles = (NCNT + SCAN_TILE - 1) / SCAN_TILE;     // 440
    k_scan_tile<<<ntiles, SCAN_TILE, 0, stream>>>(mcnt, combst, tsum);
    k_scan_tsum<<<1, SCAN_TILE, 0, stream>>>(tsum, ntiles, mstart, cstart);
    k_scan_add<<<(NCNT + 255) / 256, 256, 0, stream>>>(combst, tsum, mstart, cstart);

    // fragment means + U MLP (bf16 pipeline)
    k_frag_mean<<<(N_FRAGS + 7) / 8, 256, 0, stream>>>((const float4*)x, mapper, startb,
                                                       (ushort4*)frag16);
    k_rowmat_mfma<true, true><<<(N_FRAGS + 63) / 64, 256, 0, stream>>>(
        frag16, wfragU, b_u, frag16, N_FRAGS);                           // fragu16 in place

    // mapper CSR values, node pooling, W_gcn
    k_fill_m<<<(N_FRAG_NODES + 255) / 256, 256, 0, stream>>>(mapper, batch, mstart, mcnt, mvals);
    k_pool_csr<<<(N_NODES + 15) / 16, 256, 0, stream>>>((const float4*)x, (const u16x8*)frag16,
                                                        mstart, mvals, (u16x8*)pooled16);
    k_rowmat_mfma<false, false><<<(N_NODES + 63) / 64, 256, 0, stream>>>(
        pooled16, wfragG, nullptr, pooled16, N_NODES);                   // pw16 in place

    // edge CSR (packed records, keyed by target; edge weight computed inline)
    k_fill_e<<<(NEDGE + 255) / 256, 256, 0, stream>>>(erow, ecol, mapper, cstart, ccnt, erecs);

    // GCN aggregation (gather, bf16 rows) -> f32 x_out
    k_gcn_gather<<<(N_FRAG_NODES + 15) / 16, 256, 0, stream>>>(mapper, cstart, erecs,
                                                               (const u16x8*)pooled16,
                                                               b_gcn, (float4*)xout);
    // fragment mean of x_out
    k_frag_x<<<(N_FRAGS + 7) / 8, 256, 0, stream>>>((const float4*)xout, startb, (float4*)fout);
}